// Round 4
// baseline (404.845 us; speedup 1.0000x reference)
//
#include <hip/hip_runtime.h>
#include <hip/hip_bf16.h>
#include <math.h>

#define NPTS 2000000
#define NCL 64
#define EPSF 1e-8f
#define NB_SUMS 2048
#define NB_INTRA 2048
#define NREP 64  // global partial replicas for pass-1 flush

// ws float layout:
//   part[NREP][1088]   @ 0        (sums[c][d] at c*16+d, counts at 1024+c)
//   ticket1, ticket2   @ 69632    (ints)
//   means[1024]        @ 69636
//   icnt[64]           @ 70660
//   scal[2]            @ 70724    (inter_loss, reg_loss)
//   pintra[NB_INTRA]   @ 70726
#define WS_PART   0
#define WS_TKT1   69632
#define WS_TKT2   69633
#define WS_MEANS  69636
#define WS_ICNT   70660
#define WS_SCAL   70724
#define WS_PINTRA 70726
#define WS_ZERO_FLOATS 69634  // part + tickets must be zeroed each call

typedef __attribute__((ext_vector_type(8))) short bf16x8;
typedef __attribute__((ext_vector_type(4))) float f32x4;

__device__ __forceinline__ unsigned pk2(float a, float b) {
    __hip_bfloat162 h = __float22bfloat162_rn(make_float2(a, b));
    union { __hip_bfloat162 h; unsigned u; } x;
    x.h = h;
    return x.u;  // low 16 = a, high 16 = b
}
__device__ __forceinline__ unsigned oh2(int a, int b, int c) {
    return (a == c ? 0x3F80u : 0u) | (b == c ? 0x3F800000u : 0u);  // bf16 {1.0,1.0}
}

// Pass 1: segment-sum via one-hot MFMA (verified R3). Flush to NREP global
// replicas; LAST block (ticket) reduces them and computes means/icnt/inter/reg.
__global__ void __launch_bounds__(256) k_sums(const float4* __restrict__ feat,
                                              const int* __restrict__ lab,
                                              float* __restrict__ ws) {
    __shared__ __align__(16) float smem[4 * 1088];
    __shared__ int s_last;
    const int tid = threadIdx.x;
    const int l = tid & 63, w = tid >> 6, g = l >> 4, mcol = l & 15;

    const unsigned lds0 = (unsigned)(uintptr_t)(&smem[0]);
    const unsigned trb = lds0 + (unsigned)(w * 2048 + l * 8);
    uint2* tw = (uint2*)((unsigned short*)smem + w * 1024);

    f32x4 accS[4], accC[4];
#pragma unroll
    for (int i = 0; i < 4; ++i) {
        accS[i] = (f32x4){0.f, 0.f, 0.f, 0.f};
        accC[i] = (f32x4){0.f, 0.f, 0.f, 0.f};
    }
    bf16x8 ones;
#pragma unroll
    for (int i = 0; i < 8; ++i) ones[i] = (short)0x3F80;

    const int wstride = gridDim.x * 4;
    for (int wc = blockIdx.x * 4 + w; wc * 64 < NPTS; wc += wstride) {
        const int P = wc * 64;
        float4 f0 = feat[P * 4 + l];
        float4 f1 = feat[P * 4 + 64 + l];
        float4 f2 = feat[P * 4 + 128 + l];
        float4 f3 = feat[P * 4 + 192 + l];
        int4 La0 = *(const int4*)(lab + P + 4 * g);
        int4 Lb0 = *(const int4*)(lab + P + 16 + 4 * g);
        int4 La1 = *(const int4*)(lab + P + 32 + 4 * g);
        int4 Lb1 = *(const int4*)(lab + P + 48 + 4 * g);

        tw[l]       = make_uint2(pk2(f0.x, f0.y), pk2(f0.z, f0.w));
        tw[64 + l]  = make_uint2(pk2(f1.x, f1.y), pk2(f1.z, f1.w));
        tw[128 + l] = make_uint2(pk2(f2.x, f2.y), pk2(f2.z, f2.w));
        tw[192 + l] = make_uint2(pk2(f3.x, f3.y), pk2(f3.z, f3.w));

        asm volatile("s_waitcnt lgkmcnt(0)" ::: "memory");
        unsigned long long t00, t01, t10, t11;
        asm volatile("ds_read_b64_tr_b16 %0, %1 offset:0"    : "=v"(t00) : "v"(trb));
        asm volatile("ds_read_b64_tr_b16 %0, %1 offset:512"  : "=v"(t01) : "v"(trb));
        asm volatile("ds_read_b64_tr_b16 %0, %1 offset:1024" : "=v"(t10) : "v"(trb));
        asm volatile("ds_read_b64_tr_b16 %0, %1 offset:1536" : "=v"(t11) : "v"(trb));
        asm volatile("s_waitcnt lgkmcnt(0)" ::: "memory");
        __builtin_amdgcn_sched_barrier(0);

        union { unsigned u[4]; bf16x8 h; } B0, B1;
        B0.u[0] = (unsigned)t00; B0.u[1] = (unsigned)(t00 >> 32);
        B0.u[2] = (unsigned)t01; B0.u[3] = (unsigned)(t01 >> 32);
        B1.u[0] = (unsigned)t10; B1.u[1] = (unsigned)(t10 >> 32);
        B1.u[2] = (unsigned)t11; B1.u[3] = (unsigned)(t11 >> 32);

#pragma unroll
        for (int gp = 0; gp < 4; ++gp) {
            const int c = mcol + (gp << 4);
            union { unsigned u[4]; bf16x8 h; } A0, A1;
            A0.u[0] = oh2(La0.x, La0.y, c); A0.u[1] = oh2(La0.z, La0.w, c);
            A0.u[2] = oh2(Lb0.x, Lb0.y, c); A0.u[3] = oh2(Lb0.z, Lb0.w, c);
            A1.u[0] = oh2(La1.x, La1.y, c); A1.u[1] = oh2(La1.z, La1.w, c);
            A1.u[2] = oh2(Lb1.x, Lb1.y, c); A1.u[3] = oh2(Lb1.z, Lb1.w, c);
            accS[gp] = __builtin_amdgcn_mfma_f32_16x16x32_bf16(A0.h, B0.h, accS[gp], 0, 0, 0);
            accC[gp] = __builtin_amdgcn_mfma_f32_16x16x32_bf16(A0.h, ones, accC[gp], 0, 0, 0);
            accS[gp] = __builtin_amdgcn_mfma_f32_16x16x32_bf16(A1.h, B1.h, accS[gp], 0, 0, 0);
            accC[gp] = __builtin_amdgcn_mfma_f32_16x16x32_bf16(A1.h, ones, accC[gp], 0, 0, 0);
        }
    }

    // per-wave flush to LDS; D layout col=lane&15, row=(lane>>4)*4+reg
    __syncthreads();
    float* fl = smem + w * 1088;
#pragma unroll
    for (int gp = 0; gp < 4; ++gp) {
#pragma unroll
        for (int r = 0; r < 4; ++r) {
            int c = (gp << 4) + ((l >> 4) << 2) + r;
            fl[c * 16 + mcol] = accS[gp][r];
            if (mcol == 0) fl[1024 + c] = accC[gp][r];
        }
    }
    __syncthreads();
    float* dst = ws + WS_PART + (unsigned)(blockIdx.x & (NREP - 1)) * 1088;
    for (int i = tid; i < 1088; i += 256) {
        float s = smem[i] + smem[1088 + i] + smem[2176 + i] + smem[3264 + i];
        unsafeAtomicAdd(&dst[i], s);
    }
    __threadfence();
    __syncthreads();
    if (tid == 0)
        s_last = (atomicAdd((int*)(ws + WS_TKT1), 1) == (int)gridDim.x - 1) ? 1 : 0;
    __syncthreads();
    if (!s_last) return;

    // ---- last block: reduce NREP replicas -> means/icnt/inter/reg ----
    __threadfence();  // acquire: invalidate L1, see all replicas
    const int pg = tid >> 6, jl = tid & 63;
    for (int j = jl; j < 1088; j += 64) {
        float s = 0.f;
#pragma unroll
        for (int pp = 0; pp < 16; ++pp)
            s += ws[WS_PART + (pg * 16 + pp) * 1088 + j];
        smem[pg * 1088 + j] = s;
    }
    __syncthreads();
    for (int j = tid; j < 1088; j += 256)
        smem[j] = smem[j] + smem[1088 + j] + smem[2176 + j] + smem[3264 + j];
    __syncthreads();
    // means into global + padded LDS copy at smem[1088..2175]
    for (int i = tid; i < 1024; i += 256) {
        float m = smem[i] / smem[1024 + (i >> 4)];
        ws[WS_MEANS + i] = m;
        smem[1088 + (i >> 4) * 17 + (i & 15)] = m;
    }
    if (tid < NCL) ws[WS_ICNT + tid] = 1.0f / smem[1024 + tid];
    __syncthreads();

    const float* s_means = smem + 1088;
    float inter = 0.f;
    for (int pr = tid; pr < NCL * NCL; pr += 256) {
        int i = pr >> 6, j = pr & 63;
        if (i != j) {
            float ss = 0.f;
#pragma unroll
            for (int k = 0; k < 16; ++k) {
                float dv = s_means[i * 17 + k] - s_means[j * 17 + k] + EPSF;
                ss += dv * dv;
            }
            float h = fmaxf(3.0f - sqrtf(ss), 0.f);  // 2*INTER_MARGIN
            inter += h * h;
        }
    }
    float reg = 0.f;
    if (tid < NCL) {
        float ss = 0.f;
#pragma unroll
        for (int k = 0; k < 16; ++k) {
            float m = s_means[tid * 17 + k] + EPSF;
            ss += m * m;
        }
        reg = sqrtf(ss);
    }
#pragma unroll
    for (int m = 1; m < 64; m <<= 1) {
        inter += __shfl_xor(inter, m);
        reg += __shfl_xor(reg, m);
    }
    __shared__ float red8[8];
    if ((tid & 63) == 0) { red8[tid >> 6] = inter; red8[4 + (tid >> 6)] = reg; }
    __syncthreads();
    if (tid == 0) {
        ws[WS_SCAL + 0] = (red8[0] + red8[1] + red8[2] + red8[3]) / (float)(NCL * (NCL - 1));
        ws[WS_SCAL + 1] = (red8[4] + red8[5] + red8[6] + red8[7]) / (float)NCL;
    }
}

// Pass 2: acc += h^2 * inv_cnt[label] in registers; last block writes out[0].
__global__ void __launch_bounds__(256) k_intra(const float4* __restrict__ feat,
                                               const int* __restrict__ lab,
                                               float* __restrict__ ws,
                                               float* __restrict__ out) {
    __shared__ float s_m[NCL * 17];
    __shared__ float r4[4];
    __shared__ int s_last;
    const int tid = threadIdx.x;
    for (int i = tid; i < NCL * 16; i += 256)
        s_m[(i >> 4) * 17 + (i & 15)] = ws[WS_MEANS + i];
    for (int i = tid; i < NCL; i += 256) s_m[i * 17 + 16] = ws[WS_ICNT + i];
    __syncthreads();

    float acc = 0.f;
    const int total = NPTS * 4;
    const int stride = gridDim.x * 256;
    for (int idx = blockIdx.x * 256 + tid; idx < total; idx += stride) {
        int p = idx >> 2, q = idx & 3;
        int lb = lab[p];
        float4 v = feat[idx];
        const float* m = &s_m[lb * 17 + q * 4];
        float d0 = v.x - m[0] + EPSF;
        float d1 = v.y - m[1] + EPSF;
        float d2 = v.z - m[2] + EPSF;
        float d3 = v.w - m[3] + EPSF;
        float ss = d0 * d0 + d1 * d1 + d2 * d2 + d3 * d3;
        ss += __shfl_xor(ss, 1);
        ss += __shfl_xor(ss, 2);
        if (q == 0) {
            float h = fmaxf(sqrtf(ss) - 0.5f, 0.f);
            acc += h * h * s_m[lb * 17 + 16];
        }
    }
#pragma unroll
    for (int mm = 1; mm < 64; mm <<= 1) acc += __shfl_xor(acc, mm);
    if ((tid & 63) == 0) r4[tid >> 6] = acc;
    __syncthreads();
    if (tid == 0) ws[WS_PINTRA + blockIdx.x] = r4[0] + r4[1] + r4[2] + r4[3];
    __threadfence();
    __syncthreads();
    if (tid == 0)
        s_last = (atomicAdd((int*)(ws + WS_TKT2), 1) == (int)gridDim.x - 1) ? 1 : 0;
    __syncthreads();
    if (!s_last) return;

    __threadfence();  // acquire
    float v = 0.f;
#pragma unroll
    for (int i = 0; i < NB_INTRA / 256; ++i) v += ws[WS_PINTRA + tid + i * 256];
#pragma unroll
    for (int mm = 1; mm < 64; mm <<= 1) v += __shfl_xor(v, mm);
    if ((tid & 63) == 0) r4[tid >> 6] = v;
    __syncthreads();
    if (tid == 0)
        out[0] = (r4[0] + r4[1] + r4[2] + r4[3]) / (float)NCL +
                 ws[WS_SCAL + 0] + 0.001f * ws[WS_SCAL + 1];
}

extern "C" void kernel_launch(void* const* d_in, const int* in_sizes, int n_in,
                              void* d_out, int out_size, void* d_ws, size_t ws_size,
                              hipStream_t stream) {
    const float4* feat = (const float4*)d_in[0];
    const int* lab = (const int*)d_in[1];
    float* ws = (float*)d_ws;
    float* out = (float*)d_out;

    hipMemsetAsync(d_ws, 0, WS_ZERO_FLOATS * sizeof(float), stream);
    k_sums<<<NB_SUMS, 256, 0, stream>>>(feat, lab, ws);
    k_intra<<<NB_INTRA, 256, 0, stream>>>(feat, lab, ws, out);
}

// Round 5
// 404.518 us; speedup vs baseline: 1.0008x; 1.0008x over previous
//
#include <hip/hip_runtime.h>
#include <hip/hip_bf16.h>
#include <math.h>

#define NPTS 2000000
#define NCL 64
#define EPSF 1e-8f
#define NB_SUMS 2048
#define NB_INTRA 2048
#define NREP 64  // global partial replicas for pass-1 flush

// ws float layout:
//   part[NREP][1088]   @ 0        (sums[c][d] at c*16+d, counts at 1024+c)
//   ticket1, ticket2   @ 69632    (ints)
//   means[1024]        @ 69636
//   icnt[64]           @ 70660
//   scal[2]            @ 70724    (inter_loss, reg_loss)
//   pintra[NB_INTRA]   @ 70726
#define WS_PART   0
#define WS_TKT1   69632
#define WS_TKT2   69633
#define WS_MEANS  69636
#define WS_ICNT   70660
#define WS_SCAL   70724
#define WS_PINTRA 70726
#define WS_ZERO_FLOATS 69634  // part + tickets must be zeroed each call

typedef __attribute__((ext_vector_type(8))) short bf16x8;
typedef __attribute__((ext_vector_type(4))) float f32x4;

__device__ __forceinline__ unsigned pk2(float a, float b) {
    __hip_bfloat162 h = __float22bfloat162_rn(make_float2(a, b));
    union { __hip_bfloat162 h; unsigned u; } x;
    x.h = h;
    return x.u;  // low 16 = a, high 16 = b
}
__device__ __forceinline__ unsigned oh2(int a, int b, int c) {
    return (a == c ? 0x3F80u : 0u) | (b == c ? 0x3F800000u : 0u);  // bf16 {1.0,1.0}
}

// Pass 1: segment-sum via one-hot MFMA (verified R3). Flush to NREP global
// replicas; LAST block (ticket) reduces them and computes means/icnt/inter/reg.
__global__ void __launch_bounds__(256) k_sums(const float4* __restrict__ feat,
                                              const int* __restrict__ lab,
                                              float* __restrict__ ws) {
    __shared__ __align__(16) float smem[4 * 1088];
    __shared__ int s_last;
    const int tid = threadIdx.x;
    const int l = tid & 63, w = tid >> 6, g = l >> 4, mcol = l & 15;

    const unsigned lds0 = (unsigned)(uintptr_t)(&smem[0]);
    const unsigned trb = lds0 + (unsigned)(w * 2048 + l * 8);
    uint2* tw = (uint2*)((unsigned short*)smem + w * 1024);

    f32x4 accS[4], accC[4];
#pragma unroll
    for (int i = 0; i < 4; ++i) {
        accS[i] = (f32x4){0.f, 0.f, 0.f, 0.f};
        accC[i] = (f32x4){0.f, 0.f, 0.f, 0.f};
    }
    bf16x8 ones;
#pragma unroll
    for (int i = 0; i < 8; ++i) ones[i] = (short)0x3F80;

    const int wstride = gridDim.x * 4;
    for (int wc = blockIdx.x * 4 + w; wc * 64 < NPTS; wc += wstride) {
        const int P = wc * 64;
        float4 f0 = feat[P * 4 + l];
        float4 f1 = feat[P * 4 + 64 + l];
        float4 f2 = feat[P * 4 + 128 + l];
        float4 f3 = feat[P * 4 + 192 + l];
        int4 La0 = *(const int4*)(lab + P + 4 * g);
        int4 Lb0 = *(const int4*)(lab + P + 16 + 4 * g);
        int4 La1 = *(const int4*)(lab + P + 32 + 4 * g);
        int4 Lb1 = *(const int4*)(lab + P + 48 + 4 * g);

        tw[l]       = make_uint2(pk2(f0.x, f0.y), pk2(f0.z, f0.w));
        tw[64 + l]  = make_uint2(pk2(f1.x, f1.y), pk2(f1.z, f1.w));
        tw[128 + l] = make_uint2(pk2(f2.x, f2.y), pk2(f2.z, f2.w));
        tw[192 + l] = make_uint2(pk2(f3.x, f3.y), pk2(f3.z, f3.w));

        asm volatile("s_waitcnt lgkmcnt(0)" ::: "memory");
        unsigned long long t00, t01, t10, t11;
        asm volatile("ds_read_b64_tr_b16 %0, %1 offset:0"    : "=v"(t00) : "v"(trb));
        asm volatile("ds_read_b64_tr_b16 %0, %1 offset:512"  : "=v"(t01) : "v"(trb));
        asm volatile("ds_read_b64_tr_b16 %0, %1 offset:1024" : "=v"(t10) : "v"(trb));
        asm volatile("ds_read_b64_tr_b16 %0, %1 offset:1536" : "=v"(t11) : "v"(trb));
        asm volatile("s_waitcnt lgkmcnt(0)" ::: "memory");
        __builtin_amdgcn_sched_barrier(0);

        union { unsigned u[4]; bf16x8 h; } B0, B1;
        B0.u[0] = (unsigned)t00; B0.u[1] = (unsigned)(t00 >> 32);
        B0.u[2] = (unsigned)t01; B0.u[3] = (unsigned)(t01 >> 32);
        B1.u[0] = (unsigned)t10; B1.u[1] = (unsigned)(t10 >> 32);
        B1.u[2] = (unsigned)t11; B1.u[3] = (unsigned)(t11 >> 32);

#pragma unroll
        for (int gp = 0; gp < 4; ++gp) {
            const int c = mcol + (gp << 4);
            union { unsigned u[4]; bf16x8 h; } A0, A1;
            A0.u[0] = oh2(La0.x, La0.y, c); A0.u[1] = oh2(La0.z, La0.w, c);
            A0.u[2] = oh2(Lb0.x, Lb0.y, c); A0.u[3] = oh2(Lb0.z, Lb0.w, c);
            A1.u[0] = oh2(La1.x, La1.y, c); A1.u[1] = oh2(La1.z, La1.w, c);
            A1.u[2] = oh2(Lb1.x, Lb1.y, c); A1.u[3] = oh2(Lb1.z, Lb1.w, c);
            accS[gp] = __builtin_amdgcn_mfma_f32_16x16x32_bf16(A0.h, B0.h, accS[gp], 0, 0, 0);
            accC[gp] = __builtin_amdgcn_mfma_f32_16x16x32_bf16(A0.h, ones, accC[gp], 0, 0, 0);
            accS[gp] = __builtin_amdgcn_mfma_f32_16x16x32_bf16(A1.h, B1.h, accS[gp], 0, 0, 0);
            accC[gp] = __builtin_amdgcn_mfma_f32_16x16x32_bf16(A1.h, ones, accC[gp], 0, 0, 0);
        }
    }

    // per-wave flush to LDS; D layout col=lane&15, row=(lane>>4)*4+reg
    __syncthreads();
    float* fl = smem + w * 1088;
#pragma unroll
    for (int gp = 0; gp < 4; ++gp) {
#pragma unroll
        for (int r = 0; r < 4; ++r) {
            int c = (gp << 4) + ((l >> 4) << 2) + r;
            fl[c * 16 + mcol] = accS[gp][r];
            if (mcol == 0) fl[1024 + c] = accC[gp][r];
        }
    }
    __syncthreads();
    float* dst = ws + WS_PART + (unsigned)(blockIdx.x & (NREP - 1)) * 1088;
    for (int i = tid; i < 1088; i += 256) {
        float s = smem[i] + smem[1088 + i] + smem[2176 + i] + smem[3264 + i];
        unsafeAtomicAdd(&dst[i], s);
    }
    __threadfence();
    __syncthreads();
    if (tid == 0)
        s_last = (atomicAdd((int*)(ws + WS_TKT1), 1) == (int)gridDim.x - 1) ? 1 : 0;
    __syncthreads();
    if (!s_last) return;

    // ---- last block: reduce NREP replicas -> means/icnt/inter/reg ----
    __threadfence();  // acquire: invalidate L1, see all replicas
    const int pg = tid >> 6, jl = tid & 63;
    for (int j = jl; j < 1088; j += 64) {
        float s = 0.f;
#pragma unroll
        for (int pp = 0; pp < 16; ++pp)
            s += ws[WS_PART + (pg * 16 + pp) * 1088 + j];
        smem[pg * 1088 + j] = s;
    }
    __syncthreads();
    for (int j = tid; j < 1088; j += 256)
        smem[j] = smem[j] + smem[1088 + j] + smem[2176 + j] + smem[3264 + j];
    __syncthreads();
    // means into global + padded LDS copy at smem[1088..2175]
    for (int i = tid; i < 1024; i += 256) {
        float m = smem[i] / smem[1024 + (i >> 4)];
        ws[WS_MEANS + i] = m;
        smem[1088 + (i >> 4) * 17 + (i & 15)] = m;
    }
    if (tid < NCL) ws[WS_ICNT + tid] = 1.0f / smem[1024 + tid];
    __syncthreads();

    const float* s_means = smem + 1088;
    float inter = 0.f;
    for (int pr = tid; pr < NCL * NCL; pr += 256) {
        int i = pr >> 6, j = pr & 63;
        if (i != j) {
            float ss = 0.f;
#pragma unroll
            for (int k = 0; k < 16; ++k) {
                float dv = s_means[i * 17 + k] - s_means[j * 17 + k] + EPSF;
                ss += dv * dv;
            }
            float h = fmaxf(3.0f - sqrtf(ss), 0.f);  // 2*INTER_MARGIN
            inter += h * h;
        }
    }
    float reg = 0.f;
    if (tid < NCL) {
        float ss = 0.f;
#pragma unroll
        for (int k = 0; k < 16; ++k) {
            float m = s_means[tid * 17 + k] + EPSF;
            ss += m * m;
        }
        reg = sqrtf(ss);
    }
#pragma unroll
    for (int m = 1; m < 64; m <<= 1) {
        inter += __shfl_xor(inter, m);
        reg += __shfl_xor(reg, m);
    }
    __shared__ float red8[8];
    if ((tid & 63) == 0) { red8[tid >> 6] = inter; red8[4 + (tid >> 6)] = reg; }
    __syncthreads();
    if (tid == 0) {
        ws[WS_SCAL + 0] = (red8[0] + red8[1] + red8[2] + red8[3]) / (float)(NCL * (NCL - 1));
        ws[WS_SCAL + 1] = (red8[4] + red8[5] + red8[6] + red8[7]) / (float)NCL;
    }
}

// Pass 2: acc += h^2 * inv_cnt[label] in registers; last block writes out[0].
__global__ void __launch_bounds__(256) k_intra(const float4* __restrict__ feat,
                                               const int* __restrict__ lab,
                                               float* __restrict__ ws,
                                               float* __restrict__ out) {
    __shared__ float s_m[NCL * 17];
    __shared__ float r4[4];
    __shared__ int s_last;
    const int tid = threadIdx.x;
    for (int i = tid; i < NCL * 16; i += 256)
        s_m[(i >> 4) * 17 + (i & 15)] = ws[WS_MEANS + i];
    for (int i = tid; i < NCL; i += 256) s_m[i * 17 + 16] = ws[WS_ICNT + i];
    __syncthreads();

    float acc = 0.f;
    const int total = NPTS * 4;
    const int stride = gridDim.x * 256;
    for (int idx = blockIdx.x * 256 + tid; idx < total; idx += stride) {
        int p = idx >> 2, q = idx & 3;
        int lb = lab[p];
        float4 v = feat[idx];
        const float* m = &s_m[lb * 17 + q * 4];
        float d0 = v.x - m[0] + EPSF;
        float d1 = v.y - m[1] + EPSF;
        float d2 = v.z - m[2] + EPSF;
        float d3 = v.w - m[3] + EPSF;
        float ss = d0 * d0 + d1 * d1 + d2 * d2 + d3 * d3;
        ss += __shfl_xor(ss, 1);
        ss += __shfl_xor(ss, 2);
        if (q == 0) {
            float h = fmaxf(sqrtf(ss) - 0.5f, 0.f);
            acc += h * h * s_m[lb * 17 + 16];
        }
    }
#pragma unroll
    for (int mm = 1; mm < 64; mm <<= 1) acc += __shfl_xor(acc, mm);
    if ((tid & 63) == 0) r4[tid >> 6] = acc;
    __syncthreads();
    if (tid == 0) ws[WS_PINTRA + blockIdx.x] = r4[0] + r4[1] + r4[2] + r4[3];
    __threadfence();
    __syncthreads();
    if (tid == 0)
        s_last = (atomicAdd((int*)(ws + WS_TKT2), 1) == (int)gridDim.x - 1) ? 1 : 0;
    __syncthreads();
    if (!s_last) return;

    __threadfence();  // acquire
    float v = 0.f;
#pragma unroll
    for (int i = 0; i < NB_INTRA / 256; ++i) v += ws[WS_PINTRA + tid + i * 256];
#pragma unroll
    for (int mm = 1; mm < 64; mm <<= 1) v += __shfl_xor(v, mm);
    if ((tid & 63) == 0) r4[tid >> 6] = v;
    __syncthreads();
    if (tid == 0)
        out[0] = (r4[0] + r4[1] + r4[2] + r4[3]) / (float)NCL +
                 ws[WS_SCAL + 0] + 0.001f * ws[WS_SCAL + 1];
}

extern "C" void kernel_launch(void* const* d_in, const int* in_sizes, int n_in,
                              void* d_out, int out_size, void* d_ws, size_t ws_size,
                              hipStream_t stream) {
    const float4* feat = (const float4*)d_in[0];
    const int* lab = (const int*)d_in[1];
    float* ws = (float*)d_ws;
    float* out = (float*)d_out;

    hipMemsetAsync(d_ws, 0, WS_ZERO_FLOATS * sizeof(float), stream);
    k_sums<<<NB_SUMS, 256, 0, stream>>>(feat, lab, ws);
    k_intra<<<NB_INTRA, 256, 0, stream>>>(feat, lab, ws, out);
}